// Round 1
// baseline (731.347 us; speedup 1.0000x reference)
//
#include <hip/hip_runtime.h>

// SpatialAttention (CSWin idx=0, 8x8 windows): B=4, H=W=256, C=192, NH=6, hd=32.
// R1: fp32 vector baseline. Kernel A builds rpb[6][64][64] in d_ws via the
// RPE MLP; kernel B = one wave per (window, head), lane = query token.

#define NTOK  64      // tokens per 8x8 window
#define NHEAD 6
#define HD    32      // head dim
#define CDIM  192
#define POSD  12
#define MROWS 225     // (2*8-1)^2 relative positions
#define SCALE 0.17677669529663687f   // 32^-0.5

// ---------------------------------------------------------------- RPE MLP ---
__device__ __forceinline__ void ln_relu(const float* x, float* r,
                                        const float* __restrict__ g,
                                        const float* __restrict__ b) {
  float mean = 0.f;
#pragma unroll
  for (int j = 0; j < POSD; ++j) mean += x[j];
  mean *= (1.0f / POSD);
  float var = 0.f;
#pragma unroll
  for (int j = 0; j < POSD; ++j) { float d = x[j] - mean; var += d * d; }
  var *= (1.0f / POSD);
  const float rstd = rsqrtf(var + 1e-5f);
#pragma unroll
  for (int j = 0; j < POSD; ++j) {
    float t = (x[j] - mean) * rstd * g[j] + b[j];
    r[j] = t > 0.f ? t : 0.f;
  }
}

__global__ __launch_bounds__(256) void rpe_mlp_kernel(
    const float* __restrict__ w_proj, const float* __restrict__ b_proj,
    const float* __restrict__ ln1_g, const float* __restrict__ ln1_b,
    const float* __restrict__ w1,    const float* __restrict__ b1,
    const float* __restrict__ ln2_g, const float* __restrict__ ln2_b,
    const float* __restrict__ w2,    const float* __restrict__ b2,
    const float* __restrict__ ln3_g, const float* __restrict__ ln3_b,
    const float* __restrict__ w3,    const float* __restrict__ b3,
    float* __restrict__ rpb)
{
  __shared__ float pos_s[MROWS * NHEAD];
  const int m = threadIdx.x;
  if (m < MROWS) {
    const float bh = (float)(m / 15 - 7);
    const float bw = (float)(m % 15 - 7);
    float x[POSD], r[POSD];
#pragma unroll
    for (int j = 0; j < POSD; ++j)
      x[j] = bh * w_proj[j] + bw * w_proj[POSD + j] + b_proj[j];

    ln_relu(x, r, ln1_g, ln1_b);
#pragma unroll
    for (int j = 0; j < POSD; ++j) {
      float a = b1[j];
#pragma unroll
      for (int kk = 0; kk < POSD; ++kk) a += r[kk] * w1[kk * POSD + j];
      x[j] = a;
    }
    ln_relu(x, r, ln2_g, ln2_b);
#pragma unroll
    for (int j = 0; j < POSD; ++j) {
      float a = b2[j];
#pragma unroll
      for (int kk = 0; kk < POSD; ++kk) a += r[kk] * w2[kk * POSD + j];
      x[j] = a;
    }
    ln_relu(x, r, ln3_g, ln3_b);
#pragma unroll
    for (int hh = 0; hh < NHEAD; ++hh) {
      float a = b3[hh];
#pragma unroll
      for (int kk = 0; kk < POSD; ++kk) a += r[kk] * w3[kk * NHEAD + hh];
      pos_s[m * NHEAD + hh] = a;
    }
  }
  __syncthreads();
  // expand to rpb[h][i][j]
  for (int idx = threadIdx.x; idx < NHEAD * NTOK * NTOK; idx += blockDim.x) {
    const int h = idx >> 12;          // / 4096
    const int r = idx & 4095;
    const int i = r >> 6, j = r & 63;
    const int dy = (i >> 3) - (j >> 3) + 7;
    const int dx = (i & 7) - (j & 7) + 7;
    rpb[idx] = pos_s[(dy * 15 + dx) * NHEAD + h];
  }
}

// ------------------------------------------------------------- attention ---
__global__ __launch_bounds__(64) void attn_kernel(
    const float* __restrict__ q, const float* __restrict__ k,
    const float* __restrict__ v, const float* __restrict__ rpb,
    float* __restrict__ out)
{
  __shared__ float Ks[NTOK * HD];   // 8 KB
  __shared__ float Vs[NTOK * HD];   // 8 KB

  const int w  = blockIdx.x;        // window id: b*1024 + wy*32 + wx
  const int h  = blockIdx.y;        // head
  const int b  = w >> 10;
  const int wy = (w >> 5) & 31;
  const int wx = w & 31;
  const int tid = threadIdx.x;      // = query token i in window

  // global base of this window's head slice (128B-aligned; token stride 768B)
  const int gbase = ((b * 256 + wy * 8) * 256 + wx * 8) * CDIM + h * HD;

  // ---- stage K, V tiles into LDS (8 rows x 8 float4 per pass) ----
  {
    const int vec = tid & 7;
#pragma unroll
    for (int p = 0; p < 8; ++p) {
      const int r  = p * 8 + (tid >> 3);
      const int go = gbase + ((r >> 3) * 256 + (r & 7)) * CDIM + vec * 4;
      float4 kk = *(const float4*)(k + go);
      float4 vv = *(const float4*)(v + go);
      ((float4*)Ks)[r * 8 + vec] = kk;
      ((float4*)Vs)[r * 8 + vec] = vv;
    }
  }

  // ---- q row into registers (pre-scaled) ----
  float qreg[HD];
  {
    const int go = gbase + ((tid >> 3) * 256 + (tid & 7)) * CDIM;
#pragma unroll
    for (int t = 0; t < 8; ++t) {
      float4 f = *(const float4*)(q + go + t * 4);
      qreg[4 * t + 0] = f.x * SCALE;
      qreg[4 * t + 1] = f.y * SCALE;
      qreg[4 * t + 2] = f.z * SCALE;
      qreg[4 * t + 3] = f.w * SCALE;
    }
  }

  // ---- scores init = rpb row (lane i reads rpb[h][i][0..63]) ----
  float s[NTOK];
  {
    const float4* rp4 = (const float4*)(rpb + h * (NTOK * NTOK) + tid * NTOK);
#pragma unroll
    for (int t = 0; t < 16; ++t) {
      float4 f = rp4[t];
      s[4 * t + 0] = f.x; s[4 * t + 1] = f.y;
      s[4 * t + 2] = f.z; s[4 * t + 3] = f.w;
    }
  }

  __syncthreads();

  // ---- QK^T: s[j] += q . K[j]  (LDS reads are wave-uniform -> broadcast) ----
  const float4* Ks4 = (const float4*)Ks;
#pragma unroll
  for (int j = 0; j < NTOK; ++j) {
    float acc = 0.f;
#pragma unroll
    for (int d = 0; d < 8; ++d) {
      float4 kk = Ks4[j * 8 + d];
      acc += qreg[4 * d + 0] * kk.x + qreg[4 * d + 1] * kk.y +
             qreg[4 * d + 2] * kk.z + qreg[4 * d + 3] * kk.w;
    }
    s[j] += acc;
  }

  // ---- softmax over j (per-lane, registers) ----
  float mx = s[0];
#pragma unroll
  for (int j = 1; j < NTOK; ++j) mx = fmaxf(mx, s[j]);
  float sum = 0.f;
#pragma unroll
  for (int j = 0; j < NTOK; ++j) {
    float e = __expf(s[j] - mx);
    s[j] = e;
    sum += e;
  }
  const float inv = 1.0f / sum;

  // ---- P.V ----
  float o[HD];
#pragma unroll
  for (int d = 0; d < HD; ++d) o[d] = 0.f;
  const float4* Vs4 = (const float4*)Vs;
#pragma unroll
  for (int j = 0; j < NTOK; ++j) {
    const float p = s[j];
#pragma unroll
    for (int d = 0; d < 8; ++d) {
      float4 vv = Vs4[j * 8 + d];
      o[4 * d + 0] += p * vv.x;
      o[4 * d + 1] += p * vv.y;
      o[4 * d + 2] += p * vv.z;
      o[4 * d + 3] += p * vv.w;
    }
  }

  // ---- store (output layout (B,H,W,C) == input token layout) ----
  {
    const int go = gbase + ((tid >> 3) * 256 + (tid & 7)) * CDIM;
#pragma unroll
    for (int t = 0; t < 8; ++t) {
      float4 f = make_float4(o[4 * t + 0] * inv, o[4 * t + 1] * inv,
                             o[4 * t + 2] * inv, o[4 * t + 3] * inv);
      *(float4*)(out + go + t * 4) = f;
    }
  }
}

// ----------------------------------------------------------------- launch ---
extern "C" void kernel_launch(void* const* d_in, const int* in_sizes, int n_in,
                              void* d_out, int out_size, void* d_ws, size_t ws_size,
                              hipStream_t stream)
{
  const float* q      = (const float*)d_in[0];
  const float* k      = (const float*)d_in[1];
  const float* v      = (const float*)d_in[2];
  // d_in[3]=H, d_in[4]=W (fixed 256x256 for this problem)
  const float* w_proj = (const float*)d_in[5];
  const float* b_proj = (const float*)d_in[6];
  const float* ln1_g  = (const float*)d_in[7];
  const float* ln1_b  = (const float*)d_in[8];
  const float* w1     = (const float*)d_in[9];
  const float* b1     = (const float*)d_in[10];
  const float* ln2_g  = (const float*)d_in[11];
  const float* ln2_b  = (const float*)d_in[12];
  const float* w2     = (const float*)d_in[13];
  const float* b2     = (const float*)d_in[14];
  const float* ln3_g  = (const float*)d_in[15];
  const float* ln3_b  = (const float*)d_in[16];
  const float* w3     = (const float*)d_in[17];
  const float* b3     = (const float*)d_in[18];
  float* out = (float*)d_out;
  float* rpb = (float*)d_ws;   // 6*64*64 floats = 96 KB

  const int B = in_sizes[0] / (256 * 256 * CDIM);   // = 4

  rpe_mlp_kernel<<<1, 256, 0, stream>>>(w_proj, b_proj, ln1_g, ln1_b, w1, b1,
                                        ln2_g, ln2_b, w2, b2, ln3_g, ln3_b,
                                        w3, b3, rpb);

  dim3 grid(B * 1024, NHEAD);
  attn_kernel<<<grid, 64, 0, stream>>>(q, k, v, rpb, out);
}

// Round 2
// 610.680 us; speedup vs baseline: 1.1976x; 1.1976x over previous
//
#include <hip/hip_runtime.h>

// SpatialAttention (CSWin idx=0, 8x8 windows): B=4, H=W=256, C=192, NH=6, hd=32.
// R2: MFMA (16x16x32 bf16). One wave per (window,head), 6 waves/block = one
// window. S^T = K*Q^T (bias as C-init, in-lane softmax), P relayout via
// wave-private LDS (stride 152B for ~2-way banks), O^T = V^T*P^T so stores
// vectorize. No __syncthreads in the attention kernel.

#define NHEAD 6
#define CDIM  192
#define POSD  12
#define SCALE 0.17677669529663687f   // 32^-0.5
#define PSTRIDE 152                  // bytes per P row in LDS (64 bf16 + pad)

typedef __attribute__((ext_vector_type(8))) short short8;
typedef __attribute__((ext_vector_type(4))) short short4v;
typedef __attribute__((ext_vector_type(4))) float f32x4;

__device__ __forceinline__ short f2bf(float f) {
  unsigned u = __float_as_uint(f);
  u = (u + 0x7FFFu + ((u >> 16) & 1u)) >> 16;   // RNE
  return (short)u;
}

__device__ __forceinline__ int tokoff(int t) {   // token -> f32 offset in (H,W,C)
  return ((t >> 3) * 256 + (t & 7)) * CDIM;
}

// ---------------------------------------------------------------- RPE MLP ---
__device__ __forceinline__ void ln_relu(const float* x, float* r,
                                        const float* __restrict__ g,
                                        const float* __restrict__ b) {
  float mean = 0.f;
#pragma unroll
  for (int j = 0; j < POSD; ++j) mean += x[j];
  mean *= (1.0f / POSD);
  float var = 0.f;
#pragma unroll
  for (int j = 0; j < POSD; ++j) { float d = x[j] - mean; var += d * d; }
  var *= (1.0f / POSD);
  const float rstd = rsqrtf(var + 1e-5f);
#pragma unroll
  for (int j = 0; j < POSD; ++j) {
    float t = (x[j] - mean) * rstd * g[j] + b[j];
    r[j] = t > 0.f ? t : 0.f;
  }
}

// 24 blocks x 256 threads. Every block recomputes the tiny MLP (225 rows),
// then writes a 1024-float slice of the swizzled bias table:
// rpb_sw[((h*4+km)*4+qt)*256 + lane*4 + r] = rpb[h][query][key]
//   query = 16*qt + (lane&15), key = 16*km + 4*(lane>>4) + r
__global__ __launch_bounds__(256) void rpe_mlp_kernel(
    const float* __restrict__ w_proj, const float* __restrict__ b_proj,
    const float* __restrict__ ln1_g, const float* __restrict__ ln1_b,
    const float* __restrict__ w1,    const float* __restrict__ b1,
    const float* __restrict__ ln2_g, const float* __restrict__ ln2_b,
    const float* __restrict__ w2,    const float* __restrict__ b2,
    const float* __restrict__ ln3_g, const float* __restrict__ ln3_b,
    const float* __restrict__ w3,    const float* __restrict__ b3,
    float* __restrict__ rpb_sw)
{
  __shared__ float pos_s[225 * NHEAD];
  const int m = threadIdx.x;
  if (m < 225) {
    const float bh = (float)(m / 15 - 7);
    const float bw = (float)(m % 15 - 7);
    float x[POSD], r[POSD];
#pragma unroll
    for (int j = 0; j < POSD; ++j)
      x[j] = bh * w_proj[j] + bw * w_proj[POSD + j] + b_proj[j];
    ln_relu(x, r, ln1_g, ln1_b);
#pragma unroll
    for (int j = 0; j < POSD; ++j) {
      float a = b1[j];
#pragma unroll
      for (int kk = 0; kk < POSD; ++kk) a += r[kk] * w1[kk * POSD + j];
      x[j] = a;
    }
    ln_relu(x, r, ln2_g, ln2_b);
#pragma unroll
    for (int j = 0; j < POSD; ++j) {
      float a = b2[j];
#pragma unroll
      for (int kk = 0; kk < POSD; ++kk) a += r[kk] * w2[kk * POSD + j];
      x[j] = a;
    }
    ln_relu(x, r, ln3_g, ln3_b);
#pragma unroll
    for (int hh = 0; hh < NHEAD; ++hh) {
      float a = b3[hh];
#pragma unroll
      for (int kk = 0; kk < POSD; ++kk) a += r[kk] * w3[kk * NHEAD + hh];
      pos_s[m * NHEAD + hh] = a;
    }
  }
  __syncthreads();

  const int base = blockIdx.x * 256 + threadIdx.x;   // 0..6143
  const int lane = base & 63;
  const int qt = (base >> 6) & 3;
  const int km = (base >> 8) & 3;
  const int h  = base >> 10;
  const int c = lane & 15, qq = lane >> 4;
  const int query = 16 * qt + c;
  f32x4 vv;
#pragma unroll
  for (int r = 0; r < 4; ++r) {
    const int key = 16 * km + 4 * qq + r;
    const int dy = (query >> 3) - (key >> 3) + 7;
    const int dx = (query & 7) - (key & 7) + 7;
    vv[r] = pos_s[(dy * 15 + dx) * NHEAD + h];
  }
  *(f32x4*)(rpb_sw + base * 4) = vv;
}

// ------------------------------------------------------------- attention ---
__global__ __launch_bounds__(384) void attn_kernel(
    const float* __restrict__ q, const float* __restrict__ k,
    const float* __restrict__ v, const float* __restrict__ rpb_sw,
    float* __restrict__ out)
{
  __shared__ char Pall[NHEAD * 64 * PSTRIDE];   // 58368 B
  const int wv   = threadIdx.x >> 6;            // head (0..5)
  const int lane = threadIdx.x & 63;
  const int c = lane & 15, qq = lane >> 4;
  char* Pb = Pall + wv * (64 * PSTRIDE);

  const int w  = blockIdx.x;                    // window: b*1024 + wy*32 + wx
  const int b  = w >> 10, wy = (w >> 5) & 31, wx = w & 31;
  const int gbase = ((b * 256 + wy * 8) * 256 + wx * 8) * CDIM + wv * 32;

  // ---- K A-frags / Q B-frags, direct global -> bf16 frag ----
  // A[m=key=c+16t][kdim=8q+j], B[n=query=c+16t][kdim=8q+j]
  short8 ka[4], qb[4];
#pragma unroll
  for (int t = 0; t < 4; ++t) {
    const int go = gbase + tokoff(16 * t + c) + 8 * qq;
    f32x4 k0 = *(const f32x4*)(k + go), k1 = *(const f32x4*)(k + go + 4);
    f32x4 q0 = *(const f32x4*)(q + go), q1 = *(const f32x4*)(q + go + 4);
#pragma unroll
    for (int j = 0; j < 4; ++j) {
      ka[t][j]     = f2bf(k0[j]);
      ka[t][4 + j] = f2bf(k1[j]);
      qb[t][j]     = f2bf(q0[j] * SCALE);
      qb[t][4 + j] = f2bf(q1[j] * SCALE);
    }
  }

  // ---- V^T A-frags: A[m=d=c+16mt][kdim=key=8q+j+32ks] (scalar gathers) ----
  short8 va[2][2];
#pragma unroll
  for (int ks = 0; ks < 2; ++ks)
#pragma unroll
    for (int mt = 0; mt < 2; ++mt) {
      short8 f;
#pragma unroll
      for (int j = 0; j < 8; ++j)
        f[j] = f2bf(v[gbase + tokoff(8 * qq + j + 32 * ks) + 16 * mt + c]);
      va[mt][ks] = f;
    }

  // ---- S^T = K*Q^T + bias (bias pre-swizzled as C-init) ----
  f32x4 acc[4][4];
#pragma unroll
  for (int km = 0; km < 4; ++km)
#pragma unroll
    for (int qt = 0; qt < 4; ++qt)
      acc[km][qt] = *((const f32x4*)rpb_sw + (wv * 16 + km * 4 + qt) * 64 + lane);
#pragma unroll
  for (int km = 0; km < 4; ++km)
#pragma unroll
    for (int qt = 0; qt < 4; ++qt)
      acc[km][qt] = __builtin_amdgcn_mfma_f32_16x16x32_bf16(
          ka[km], qb[qt], acc[km][qt], 0, 0, 0);

  // ---- softmax over keys (in-lane over km,r; cross-quad via 2 shuffles) ----
#pragma unroll
  for (int qt = 0; qt < 4; ++qt) {
    float mx = acc[0][qt][0];
#pragma unroll
    for (int km = 0; km < 4; ++km)
#pragma unroll
      for (int r = 0; r < 4; ++r) mx = fmaxf(mx, acc[km][qt][r]);
    mx = fmaxf(mx, __shfl_xor(mx, 16, 64));
    mx = fmaxf(mx, __shfl_xor(mx, 32, 64));
    float sm = 0.f;
#pragma unroll
    for (int km = 0; km < 4; ++km)
#pragma unroll
      for (int r = 0; r < 4; ++r) {
        float e = __expf(acc[km][qt][r] - mx);
        acc[km][qt][r] = e;
        sm += e;
      }
    sm += __shfl_xor(sm, 16, 64);
    sm += __shfl_xor(sm, 32, 64);
    const float inv = 1.0f / sm;
#pragma unroll
    for (int km = 0; km < 4; ++km)
#pragma unroll
      for (int r = 0; r < 4; ++r) acc[km][qt][r] *= inv;
  }

  // ---- P -> LDS [query][key] bf16 (row stride 152B; wave-private) ----
#pragma unroll
  for (int km = 0; km < 4; ++km)
#pragma unroll
    for (int qt = 0; qt < 4; ++qt) {
      short4v pk;
#pragma unroll
      for (int r = 0; r < 4; ++r) pk[r] = f2bf(acc[km][qt][r]);
      *(short4v*)(Pb + (16 * qt + c) * PSTRIDE + (16 * km + 4 * qq) * 2) = pk;
    }

  // ---- O^T = V^T * P^T ; B[kdim=key=8q+j+32ks][n=query=c+16nt] ----
  f32x4 o[2][4];
#pragma unroll
  for (int mt = 0; mt < 2; ++mt)
#pragma unroll
    for (int nt = 0; nt < 4; ++nt) o[mt][nt] = (f32x4){0.f, 0.f, 0.f, 0.f};
#pragma unroll
  for (int ks = 0; ks < 2; ++ks)
#pragma unroll
    for (int nt = 0; nt < 4; ++nt) {
      const char* rp = Pb + (16 * nt + c) * PSTRIDE + 16 * qq + 64 * ks;
      short4v p0 = *(const short4v*)rp;
      short4v p1 = *(const short4v*)(rp + 8);
      short8 pb;
#pragma unroll
      for (int j = 0; j < 4; ++j) { pb[j] = p0[j]; pb[4 + j] = p1[j]; }
#pragma unroll
      for (int mt = 0; mt < 2; ++mt)
        o[mt][nt] = __builtin_amdgcn_mfma_f32_16x16x32_bf16(
            va[mt][ks], pb, o[mt][nt], 0, 0, 0);
    }

  // ---- store O^T: lane holds O[d=16mt+4q+r][query=c+16nt], r contiguous ----
#pragma unroll
  for (int nt = 0; nt < 4; ++nt) {
    const int go = gbase + tokoff(16 * nt + c) + 4 * qq;
#pragma unroll
    for (int mt = 0; mt < 2; ++mt)
      *(f32x4*)(out + go + 16 * mt) = o[mt][nt];
  }
}

// ----------------------------------------------------------------- launch ---
extern "C" void kernel_launch(void* const* d_in, const int* in_sizes, int n_in,
                              void* d_out, int out_size, void* d_ws, size_t ws_size,
                              hipStream_t stream)
{
  const float* q      = (const float*)d_in[0];
  const float* k      = (const float*)d_in[1];
  const float* v      = (const float*)d_in[2];
  const float* w_proj = (const float*)d_in[5];
  const float* b_proj = (const float*)d_in[6];
  const float* ln1_g  = (const float*)d_in[7];
  const float* ln1_b  = (const float*)d_in[8];
  const float* w1     = (const float*)d_in[9];
  const float* b1     = (const float*)d_in[10];
  const float* ln2_g  = (const float*)d_in[11];
  const float* ln2_b  = (const float*)d_in[12];
  const float* w2     = (const float*)d_in[13];
  const float* b2     = (const float*)d_in[14];
  const float* ln3_g  = (const float*)d_in[15];
  const float* ln3_b  = (const float*)d_in[16];
  const float* w3     = (const float*)d_in[17];
  const float* b3     = (const float*)d_in[18];
  float* out = (float*)d_out;
  float* rpb_sw = (float*)d_ws;   // 6*4*4*64*4 floats = 96 KB

  const int B = in_sizes[0] / (256 * 256 * CDIM);   // = 4

  rpe_mlp_kernel<<<24, 256, 0, stream>>>(w_proj, b_proj, ln1_g, ln1_b, w1, b1,
                                         ln2_g, ln2_b, w2, b2, ln3_g, ln3_b,
                                         w3, b3, rpb_sw);

  attn_kernel<<<B * 1024, 384, 0, stream>>>(q, k, v, rpb_sw, out);
}